// Round 7
// baseline (143.548 us; speedup 1.0000x reference)
//
#include <hip/hip_runtime.h>
#include <hip/hip_bf16.h>

// Problem constants
#define BB 4
#define CC 128
#define NN 4096
#define KK 32
// ws layout (floats)
#define THETA_OFF 0
#define THETA_SZ  (BB*NN*CC)          // 2097152 floats (8 MB)
#define M_OFF     (THETA_OFF + THETA_SZ)
#define M_SZ      (CC*CC)
#define B2_OFF    (M_OFF + M_SZ)
#define COEF_OFF  (B2_OFF + 128)
#define COEF_SZ   (BB*NN*KK)
#define PART_OFF  (COEF_OFF + COEF_SZ)
#define PART_SZ   (512*256)
#define PART2_OFF (PART_OFF + PART_SZ)
#define PART2_SZ  (64*256)
#define STAT_OFF  (PART2_OFF + PART2_SZ)

__device__ __forceinline__ float dot4(float4 a, float4 b) {
    return a.x*b.x + a.y*b.y + a.z*b.z + a.w*b.w;
}

// async global->LDS DMA, 16B per lane. LDS dest is wave-uniform base
// (HW writes base + lane*16); global src is per-lane.
__device__ __forceinline__ void async_copy16(const float* g, float* l) {
    __builtin_amdgcn_global_load_lds(
        (const __attribute__((address_space(1))) void*)g,
        (__attribute__((address_space(3))) void*)l, 16, 0, 0);
}

// raw barrier without the vmcnt(0) drain that __syncthreads() emits
#define SYNCB() do { asm volatile("" ::: "memory"); \
                     __builtin_amdgcn_s_barrier(); \
                     asm volatile("" ::: "memory"); } while (0)

// ---------------- Kernel WT: theta GEMM (blocks 0..511) + weight combine (512..576) ----
__global__ __launch_bounds__(256) void kWT(const float* __restrict__ x,
                                           const float* __restrict__ Wt,
                                           const float* __restrict__ bt,
                                           const float* __restrict__ Ww,
                                           const float* __restrict__ Wg,
                                           const float* __restrict__ bg,
                                           const float* __restrict__ bw,
                                           float* __restrict__ theta,
                                           float* __restrict__ M,
                                           float* __restrict__ b2) {
    __shared__ float xr[32][132];
    __shared__ float wt[128][36];
    int t = threadIdx.x;
    if (blockIdx.x >= 512) {
        int bid2 = blockIdx.x - 512;
        if (bid2 < 64) {
            int e = bid2 * 2 + (t >> 7);
            int c = t & 127;
            float acc = 0.f;
#pragma unroll 8
            for (int d = 0; d < 128; ++d)
                acc += Ww[e*128 + d] * Wg[d*128 + c];
            M[e*128 + c] = acc;
        } else if (t < 128) {
            float acc = bw[t];
            for (int d = 0; d < 128; ++d)
                acc += Ww[t*128 + d] * bg[d];
            b2[t] = acc;
        }
        return;
    }
    long base = (long)blockIdx.x * (32 * 128);
#pragma unroll
    for (int r = 0; r < 4; ++r) {
        int f = (t + 256*r) * 4;
        int dn = f >> 7, c = f & 127;
        *(float4*)&xr[dn][c] = *(const float4*)(x + base + f);
    }
    float acc[4][4] = {};
    int e0 = t & 31, dn0 = (t >> 5) * 4;
    for (int cb = 0; cb < 4; ++cb) {
        __syncthreads();
#pragma unroll
        for (int r = 0; r < 4; ++r) {
            int f = (t + 256*r) * 4;
            int d = f >> 5, cc = f & 31;
            *(float4*)&wt[d][cc] = *(const float4*)(Wt + d*128 + cb*32 + cc);
        }
        __syncthreads();
#pragma unroll
        for (int q = 0; q < 8; ++q) {
            float4 a4[4], m4[4];
#pragma unroll
            for (int j = 0; j < 4; ++j) a4[j] = *(const float4*)&xr[dn0+j][cb*32 + q*4];
#pragma unroll
            for (int i = 0; i < 4; ++i) m4[i] = *(const float4*)&wt[e0 + 32*i][q*4];
#pragma unroll
            for (int i = 0; i < 4; ++i)
#pragma unroll
                for (int j = 0; j < 4; ++j)
                    acc[i][j] += dot4(a4[j], m4[i]);
        }
    }
    __syncthreads();
#pragma unroll
    for (int i = 0; i < 4; ++i) {
        float b = bt[e0 + 32*i];
#pragma unroll
        for (int j = 0; j < 4; ++j)
            xr[dn0 + j][e0 + 32*i] = acc[i][j] + b;
    }
    __syncthreads();
#pragma unroll
    for (int r = 0; r < 4; ++r) {
        int f = (t + 256*r) * 4;
        int dn = f >> 7, c = f & 127;
        *(float4*)(theta + base + f) = *(const float4*)&xr[dn][c];
    }
}

// ---------------- Kernel A: coef = softmax_k(theta[n] . theta[idx[n,k]]) ----------------
// XCD-bijective swizzle: each XCD works one contiguous half-batch => theta
// working set 2 MB per XCD L2.
__global__ __launch_bounds__(256) void kA(const int* __restrict__ gi,
                                          const float* __restrict__ theta,
                                          float* __restrict__ coefG) {
    __shared__ float tc[16][132];
    __shared__ float logits[16][33];
    int t = threadIdx.x;
    int bid = (blockIdx.x & 7) * 128 + (blockIdx.x >> 3);
    long trow0 = (long)bid * 16;
    int b = bid >> 8;
    int k = t >> 3, l8 = t & 7;
#pragma unroll
    for (int r = 0; r < 2; ++r) {
        int f = (t + 256*r) * 4;
        int dn = f >> 7, c = f & 127;
        *(float4*)&tc[dn][c] = *(const float4*)(theta + trow0*128 + f);
    }
    int idxs[16];
#pragma unroll
    for (int dn = 0; dn < 16; ++dn)
        idxs[dn] = gi[(trow0 + dn) * KK + k];
    __syncthreads();
    const float* tbat = theta + (long)b * NN * CC;
#pragma unroll 2
    for (int dn = 0; dn < 16; ++dn) {
        const float* row = tbat + (long)idxs[dn] * CC;
        float p = 0.f;
#pragma unroll
        for (int j = 0; j < 4; ++j) {
            int c = j*32 + l8*4;
            float4 g = *(const float4*)(row + c);
            float4 tcv = *(const float4*)&tc[dn][c];
            p += dot4(g, tcv);
        }
        p += __shfl_xor(p, 1);
        p += __shfl_xor(p, 2);
        p += __shfl_xor(p, 4);
        if (l8 == 0) logits[dn][k] = p;
    }
    __syncthreads();
    if (t < 128) {
        int row = t >> 3;
        float l[4];
#pragma unroll
        for (int j = 0; j < 4; ++j) l[j] = logits[row][l8 + 8*j];
        float m = fmaxf(fmaxf(l[0], l[1]), fmaxf(l[2], l[3]));
        m = fmaxf(m, __shfl_xor(m, 1));
        m = fmaxf(m, __shfl_xor(m, 2));
        m = fmaxf(m, __shfl_xor(m, 4));
        float e[4]; float s = 0.f;
#pragma unroll
        for (int j = 0; j < 4; ++j) { e[j] = __expf(l[j] - m); s += e[j]; }
        s += __shfl_xor(s, 1);
        s += __shfl_xor(s, 2);
        s += __shfl_xor(s, 4);
        float inv = 1.0f / s;
#pragma unroll
        for (int j = 0; j < 4; ++j)
            coefG[(trow0 + row) * KK + l8 + 8*j] = e[j] * inv;
    }
}

// ---------------- Kernel BC (fused): stream feature -> agg in LDS -> y = agg@M^T + b2 ----
// One block = 32 rows x ALL 128 channels. 512 blocks.
// Ring: 32 chunks of 4 channels; 3-slot DMA staging, 2 chunks in flight,
// counted vmcnt (never 0 until the last chunk). Each wave stages channel
// (4*ch + w); its vmcnt wait covers its own DMAs; barrier aggregates.
// GEMM phase then reads aggL directly from LDS (no global agg round-trip);
// mc/pw/qw reuse the (dead) stage buffer.
__global__ __launch_bounds__(256) void kBC(const float* __restrict__ coefG,
                                           const float* __restrict__ feat,
                                           const float* __restrict__ Mmat,
                                           const float* __restrict__ b2v,
                                           float* __restrict__ y,
                                           float* __restrict__ partial) {
    __shared__ float stage[3][4][32][32];   // 48 KB; reused in GEMM phase
    __shared__ float aggL[32][132];         // 16.9 KB
    int t = threadIdx.x;
    int tile = blockIdx.x;               // b*128 + nt
    int b = tile >> 7;
    int n0 = (tile & 127) * 32;
    int dn = t >> 3, l8 = t & 7;
    int w = t >> 6, lane = t & 63;

    float4 cf = *(const float4*)(coefG + ((size_t)tile * 32 + dn) * KK + l8 * 4);
    // force cf into registers BEFORE any DMA issues, so the compiler's
    // waitcnt for cf doesn't drain the DMA pipeline inside the loop
    asm volatile("" :: "v"(cf.x), "v"(cf.y), "v"(cf.z), "v"(cf.w));

    const size_t S = (size_t)NN * KK;
    // per-lane global base: lane L covers bytes [L*16, L*16+16) of each 1KB row-group
    const float* fbase = feat + (size_t)b * CC * S + (size_t)n0 * KK + lane * 4;

    // prologue: stage chunks 0,1,2 into slots 0,1,2
#pragma unroll
    for (int ch = 0; ch < 3; ++ch) {
        const float* fc = fbase + (size_t)(ch * 4 + w) * S;
        float* ld = &stage[ch][w][0][0];
#pragma unroll
        for (int i = 0; i < 4; ++i)
            async_copy16(fc + i * 256, ld + i * 256);
    }

    int slot = 0;
#pragma unroll
    for (int ch = 0; ch < 32; ++ch) {
        // wait until this wave's chunk-ch loads (oldest 4) are done
        int rem = 31 - ch;
        if (rem >= 2)      asm volatile("s_waitcnt vmcnt(8)" ::: "memory");
        else if (rem == 1) asm volatile("s_waitcnt vmcnt(4)" ::: "memory");
        else               asm volatile("s_waitcnt vmcnt(0)" ::: "memory");
        SYNCB();   // all waves' chunk-ch staging complete
#pragma unroll
        for (int cl = 0; cl < 4; ++cl) {
            float4 f = *(const float4*)&stage[slot][cl][dn][l8 * 4];
            float v = dot4(f, cf);
            v += __shfl_xor(v, 1);
            v += __shfl_xor(v, 2);
            v += __shfl_xor(v, 4);
            if (l8 == 0) aggL[dn][ch * 4 + cl] = v;
        }
        SYNCB();   // all waves done reading this slot before restage
        if (ch + 3 < 32) {
            const float* fc = fbase + (size_t)((ch + 3) * 4 + w) * S;
            float* ld = &stage[slot][w][0][0];
#pragma unroll
            for (int i = 0; i < 4; ++i)
                async_copy16(fc + i * 256, ld + i * 256);
        }
        slot = (slot == 2) ? 0 : slot + 1;
    }

    // ---- GEMM phase: y_tile = aggL @ M^T + b2 (stage buffer reused) ----
    float (*mc)[36]  = (float(*)[36])&stage[0][0][0][0];           // 128x36
    float (*pw)[128] = (float(*)[128])(((float*)stage) + 128*36);  // 4x128
    float (*qw)[128] = (float(*)[128])(((float*)stage) + 128*36 + 4*128);

    float acc[4][4] = {};
    int e0 = t & 31, dn0 = (t >> 5) * 4;
    for (int cb = 0; cb < 4; ++cb) {
        __syncthreads();   // prior reads of stage/aggL visible; stage safe to overwrite
#pragma unroll
        for (int r = 0; r < 4; ++r) {
            int f = (t + 256*r) * 4;
            int e = f >> 5, cc = f & 31;
            *(float4*)&mc[e][cc] = *(const float4*)(Mmat + e*128 + cb*32 + cc);
        }
        __syncthreads();
#pragma unroll
        for (int q = 0; q < 8; ++q) {
            float4 a4[4], m4[4];
#pragma unroll
            for (int j = 0; j < 4; ++j) a4[j] = *(const float4*)&aggL[dn0+j][cb*32 + q*4];
#pragma unroll
            for (int i = 0; i < 4; ++i) m4[i] = *(const float4*)&mc[e0 + 32*i][q*4];
#pragma unroll
            for (int i = 0; i < 4; ++i)
#pragma unroll
                for (int j = 0; j < 4; ++j)
                    acc[i][j] += dot4(a4[j], m4[i]);
        }
        __syncthreads();
    }
    int wv = t >> 6;
#pragma unroll
    for (int i = 0; i < 4; ++i) {
        int e = e0 + 32*i;
        float bb = b2v[e];
        float4 yv;
        yv.x = acc[i][0] + bb;
        yv.y = acc[i][1] + bb;
        yv.z = acc[i][2] + bb;
        yv.w = acc[i][3] + bb;
        *(float4*)(y + ((long)(b*CC + e)) * NN + n0 + dn0) = yv;
        float s = yv.x + yv.y + yv.z + yv.w;
        float qq = yv.x*yv.x + yv.y*yv.y + yv.z*yv.z + yv.w*yv.w;
        s  += __shfl_xor(s, 32);
        qq += __shfl_xor(qq, 32);
        if (!(t & 32)) { pw[wv][e] = s; qw[wv][e] = qq; }
    }
    __syncthreads();
    if (t < 128) {
        partial[(long)tile * 256 + t]       = pw[0][t] + pw[1][t] + pw[2][t] + pw[3][t];
        partial[(long)tile * 256 + 128 + t] = qw[0][t] + qw[1][t] + qw[2][t] + qw[3][t];
    }
}

// ---------------- Kernel R1: 512 partial rows -> 64 ----------------
__global__ __launch_bounds__(256) void kR1(const float* __restrict__ partial,
                                           float* __restrict__ partial2) {
    int t = threadIdx.x;
    long b0 = (long)blockIdx.x * 8;
    float acc = 0.f;
#pragma unroll
    for (int j = 0; j < 8; ++j)
        acc += partial[(b0 + j) * 256 + t];
    partial2[(long)blockIdx.x * 256 + t] = acc;
}

// ---------------- Kernel R2: 64 rows -> stats ----------------
__global__ __launch_bounds__(256) void kR2(const float* __restrict__ partial2,
                                           const float* __restrict__ gamma,
                                           const float* __restrict__ beta,
                                           float* __restrict__ stats) {
    __shared__ float buf[256];
    int t = threadIdx.x;
    float acc = 0.f;
#pragma unroll
    for (int j = 0; j < 64; ++j)
        acc += partial2[j * 256 + t];
    buf[t] = acc;
    __syncthreads();
    if (t < 128) {
        float S = buf[t], Q = buf[t + 128];
        const float invN = 1.0f / (BB * NN);
        float mean = S * invN;
        float var  = Q * invN - mean * mean;
        float sc = rsqrtf(var + 1e-5f) * gamma[t];
        stats[t]       = sc;
        stats[128 + t] = beta[t] - mean * sc;
    }
}

// ---------------- Kernel Z: in-place normalize ----------------
__global__ void kZ(float* __restrict__ y, const float* __restrict__ stats) {
    int idx = blockIdx.x * 256 + threadIdx.x;   // float4 index
#pragma unroll
    for (int r = 0; r < 2; ++r) {
        int i = idx + r * 262144;
        int e = (i >> 10) & 127;
        float sc = stats[e], sh = stats[128 + e];
        float4 v = ((float4*)y)[i];
        v.x = v.x * sc + sh;
        v.y = v.y * sc + sh;
        v.z = v.z * sc + sh;
        v.w = v.w * sc + sh;
        ((float4*)y)[i] = v;
    }
}

extern "C" void kernel_launch(void* const* d_in, const int* in_sizes, int n_in,
                              void* d_out, int out_size, void* d_ws, size_t ws_size,
                              hipStream_t stream) {
    const int*   gi    = (const int*)d_in[0];
    const float* x     = (const float*)d_in[1];
    const float* feat  = (const float*)d_in[2];
    const float* Wt    = (const float*)d_in[3];
    const float* bt    = (const float*)d_in[4];
    const float* Wg    = (const float*)d_in[5];
    const float* bg    = (const float*)d_in[6];
    const float* Ww    = (const float*)d_in[7];
    const float* bw    = (const float*)d_in[8];
    const float* gamma = (const float*)d_in[9];
    const float* beta  = (const float*)d_in[10];

    float* y  = (float*)d_out;
    float* ws = (float*)d_ws;
    float* theta    = ws + THETA_OFF;
    float* Mmat     = ws + M_OFF;
    float* b2       = ws + B2_OFF;
    float* coefG    = ws + COEF_OFF;
    float* partial  = ws + PART_OFF;
    float* partial2 = ws + PART2_OFF;
    float* stats    = ws + STAT_OFF;

    kWT<<<577, 256, 0, stream>>>(x, Wt, bt, Ww, Wg, bg, bw, theta, Mmat, b2);
    kA<<<1024, 256, 0, stream>>>(gi, theta, coefG);
    kBC<<<512, 256, 0, stream>>>(coefG, feat, Mmat, b2, y, partial);
    kR1<<<64, 256, 0, stream>>>(partial, partial2);
    kR2<<<1, 256, 0, stream>>>(partial2, gamma, beta, stats);
    kZ<<<1024, 256, 0, stream>>>(y, stats);
}

// Round 8
// 102.481 us; speedup vs baseline: 1.4007x; 1.4007x over previous
//
#include <hip/hip_runtime.h>
#include <hip/hip_bf16.h>

// Problem constants
#define BB 4
#define CC 128
#define NN 4096
#define KK 32
// ws layout (floats)
#define THETA_OFF 0
#define THETA_SZ  (BB*NN*CC)          // 2097152 floats (8 MB)
#define AGG_OFF   (THETA_OFF + THETA_SZ)
#define AGG_SZ    (BB*NN*CC)
#define M_OFF     (AGG_OFF + AGG_SZ)
#define M_SZ      (CC*CC)
#define B2_OFF    (M_OFF + M_SZ)
#define COEF_OFF  (B2_OFF + 128)
#define COEF_SZ   (BB*NN*KK)
#define PART_OFF  (COEF_OFF + COEF_SZ)
#define PART_SZ   (512*256)
#define PART2_OFF (PART_OFF + PART_SZ)
#define PART2_SZ  (64*256)

__device__ __forceinline__ float dot4(float4 a, float4 b) {
    return a.x*b.x + a.y*b.y + a.z*b.z + a.w*b.w;
}

// async global->LDS DMA, 16B per lane. LDS dest is wave-uniform base
// (HW writes base + lane*16); global src is per-lane.
__device__ __forceinline__ void async_copy16(const float* g, float* l) {
    __builtin_amdgcn_global_load_lds(
        (const __attribute__((address_space(1))) void*)g,
        (__attribute__((address_space(3))) void*)l, 16, 0, 0);
}

// raw barrier without the vmcnt(0) drain that __syncthreads() emits
#define SYNCB() do { asm volatile("" ::: "memory"); \
                     __builtin_amdgcn_s_barrier(); \
                     asm volatile("" ::: "memory"); } while (0)

// ---------------- Kernel WT: theta GEMM (blocks 0..511) + weight combine (512..576) ----
__global__ __launch_bounds__(256) void kWT(const float* __restrict__ x,
                                           const float* __restrict__ Wt,
                                           const float* __restrict__ bt,
                                           const float* __restrict__ Ww,
                                           const float* __restrict__ Wg,
                                           const float* __restrict__ bg,
                                           const float* __restrict__ bw,
                                           float* __restrict__ theta,
                                           float* __restrict__ M,
                                           float* __restrict__ b2) {
    __shared__ float xr[32][132];
    __shared__ float wt[128][36];
    int t = threadIdx.x;
    if (blockIdx.x >= 512) {
        int bid2 = blockIdx.x - 512;
        if (bid2 < 64) {
            int e = bid2 * 2 + (t >> 7);
            int c = t & 127;
            float acc = 0.f;
#pragma unroll 8
            for (int d = 0; d < 128; ++d)
                acc += Ww[e*128 + d] * Wg[d*128 + c];
            M[e*128 + c] = acc;
        } else if (t < 128) {
            float acc = bw[t];
            for (int d = 0; d < 128; ++d)
                acc += Ww[t*128 + d] * bg[d];
            b2[t] = acc;
        }
        return;
    }
    long base = (long)blockIdx.x * (32 * 128);
#pragma unroll
    for (int r = 0; r < 4; ++r) {
        int f = (t + 256*r) * 4;
        int dn = f >> 7, c = f & 127;
        *(float4*)&xr[dn][c] = *(const float4*)(x + base + f);
    }
    float acc[4][4] = {};
    int e0 = t & 31, dn0 = (t >> 5) * 4;
    for (int cb = 0; cb < 4; ++cb) {
        __syncthreads();
#pragma unroll
        for (int r = 0; r < 4; ++r) {
            int f = (t + 256*r) * 4;
            int d = f >> 5, cc = f & 31;
            *(float4*)&wt[d][cc] = *(const float4*)(Wt + d*128 + cb*32 + cc);
        }
        __syncthreads();
#pragma unroll
        for (int q = 0; q < 8; ++q) {
            float4 a4[4], m4[4];
#pragma unroll
            for (int j = 0; j < 4; ++j) a4[j] = *(const float4*)&xr[dn0+j][cb*32 + q*4];
#pragma unroll
            for (int i = 0; i < 4; ++i) m4[i] = *(const float4*)&wt[e0 + 32*i][q*4];
#pragma unroll
            for (int i = 0; i < 4; ++i)
#pragma unroll
                for (int j = 0; j < 4; ++j)
                    acc[i][j] += dot4(a4[j], m4[i]);
        }
    }
    __syncthreads();
#pragma unroll
    for (int i = 0; i < 4; ++i) {
        float b = bt[e0 + 32*i];
#pragma unroll
        for (int j = 0; j < 4; ++j)
            xr[dn0 + j][e0 + 32*i] = acc[i][j] + b;
    }
    __syncthreads();
#pragma unroll
    for (int r = 0; r < 4; ++r) {
        int f = (t + 256*r) * 4;
        int dn = f >> 7, c = f & 127;
        *(float4*)(theta + base + f) = *(const float4*)&xr[dn][c];
    }
}

// ---------------- Kernel A: coef = softmax_k(theta[n] . theta[idx[n,k]]) ----------------
// XCD-bijective swizzle: each XCD works one contiguous half-batch => theta
// working set 2 MB per XCD L2.
__global__ __launch_bounds__(256) void kA(const int* __restrict__ gi,
                                          const float* __restrict__ theta,
                                          float* __restrict__ coefG) {
    __shared__ float tc[16][132];
    __shared__ float logits[16][33];
    int t = threadIdx.x;
    int bid = (blockIdx.x & 7) * 128 + (blockIdx.x >> 3);
    long trow0 = (long)bid * 16;
    int b = bid >> 8;
    int k = t >> 3, l8 = t & 7;
#pragma unroll
    for (int r = 0; r < 2; ++r) {
        int f = (t + 256*r) * 4;
        int dn = f >> 7, c = f & 127;
        *(float4*)&tc[dn][c] = *(const float4*)(theta + trow0*128 + f);
    }
    int idxs[16];
#pragma unroll
    for (int dn = 0; dn < 16; ++dn)
        idxs[dn] = gi[(trow0 + dn) * KK + k];
    __syncthreads();
    const float* tbat = theta + (long)b * NN * CC;
#pragma unroll 2
    for (int dn = 0; dn < 16; ++dn) {
        const float* row = tbat + (long)idxs[dn] * CC;
        float p = 0.f;
#pragma unroll
        for (int j = 0; j < 4; ++j) {
            int c = j*32 + l8*4;
            float4 g = *(const float4*)(row + c);
            float4 tcv = *(const float4*)&tc[dn][c];
            p += dot4(g, tcv);
        }
        p += __shfl_xor(p, 1);
        p += __shfl_xor(p, 2);
        p += __shfl_xor(p, 4);
        if (l8 == 0) logits[dn][k] = p;
    }
    __syncthreads();
    if (t < 128) {
        int row = t >> 3;
        float l[4];
#pragma unroll
        for (int j = 0; j < 4; ++j) l[j] = logits[row][l8 + 8*j];
        float m = fmaxf(fmaxf(l[0], l[1]), fmaxf(l[2], l[3]));
        m = fmaxf(m, __shfl_xor(m, 1));
        m = fmaxf(m, __shfl_xor(m, 2));
        m = fmaxf(m, __shfl_xor(m, 4));
        float e[4]; float s = 0.f;
#pragma unroll
        for (int j = 0; j < 4; ++j) { e[j] = __expf(l[j] - m); s += e[j]; }
        s += __shfl_xor(s, 1);
        s += __shfl_xor(s, 2);
        s += __shfl_xor(s, 4);
        float inv = 1.0f / s;
#pragma unroll
        for (int j = 0; j < 4; ++j)
            coefG[(trow0 + row) * KK + l8 + 8*j] = e[j] * inv;
    }
}

// ---------------- Kernel B: agg[n][c] = sum_k coef[n][k]*feature[b][c][n][k] ----------------
// 2-slot DMA ring (32 KB stage -> 4 blocks/CU), 1 chunk in flight, counted
// vmcnt (never 0 until the last chunk). Each wave stages channel (4*ch+w);
// per-wave vmcnt covers its own DMAs; barrier aggregates across waves.
__global__ __launch_bounds__(256) void kB(const float* __restrict__ coefG,
                                          const float* __restrict__ feat,
                                          float* __restrict__ aggG) {
    __shared__ float stage[2][4][32][32];   // [slot][c_local][n][k] 2x16KB
    __shared__ float aggL[32][36];
    int t = threadIdx.x;
    int cc4 = blockIdx.x & 3;
    int tile = blockIdx.x >> 2;          // b*128 + nt
    int b = tile >> 7;
    int n0 = (tile & 127) * 32;
    int dn = t >> 3, l8 = t & 7;
    int w = t >> 6, lane = t & 63;

    float4 cf = *(const float4*)(coefG + ((size_t)tile * 32 + dn) * KK + l8 * 4);
    // force cf into registers BEFORE any DMA issues, so the compiler's
    // waitcnt for cf doesn't drain the DMA pipeline inside the loop
    asm volatile("" :: "v"(cf.x), "v"(cf.y), "v"(cf.z), "v"(cf.w));

    const size_t S = (size_t)NN * KK;
    // per-lane global base: lane L covers bytes [L*16, L*16+16) of each 1KB row-group
    const float* fbase = feat + ((size_t)b * CC + cc4 * 32) * S + (size_t)n0 * KK + lane * 4;

    // prologue: stage chunks 0,1 into slots 0,1
#pragma unroll
    for (int ch = 0; ch < 2; ++ch) {
        const float* fc = fbase + (size_t)(ch * 4 + w) * S;
        float* ld = &stage[ch][w][0][0];
#pragma unroll
        for (int i = 0; i < 4; ++i)
            async_copy16(fc + i * 256, ld + i * 256);
    }

    int slot = 0;
#pragma unroll
    for (int ch = 0; ch < 8; ++ch) {
        // wait until this wave's chunk-ch loads (oldest 4) are done
        if (ch < 7) asm volatile("s_waitcnt vmcnt(4)" ::: "memory");
        else        asm volatile("s_waitcnt vmcnt(0)" ::: "memory");
        SYNCB();   // all waves' chunk-ch staging complete
#pragma unroll
        for (int cl = 0; cl < 4; ++cl) {
            float4 f = *(const float4*)&stage[slot][cl][dn][l8 * 4];
            float v = dot4(f, cf);
            v += __shfl_xor(v, 1);
            v += __shfl_xor(v, 2);
            v += __shfl_xor(v, 4);
            if (l8 == 0) aggL[dn][ch * 4 + cl] = v;
        }
        SYNCB();   // all waves done reading this slot before restage
        if (ch + 2 < 8) {
            const float* fc = fbase + (size_t)((ch + 2) * 4 + w) * S;
            float* ld = &stage[slot][w][0][0];
#pragma unroll
            for (int i = 0; i < 4; ++i)
                async_copy16(fc + i * 256, ld + i * 256);
        }
        slot ^= 1;
    }
    __syncthreads();
    int row = t >> 3, col4 = l8 * 4;
    *(float4*)(aggG + ((size_t)b * NN + n0 + row) * CC + cc4 * 32 + col4) =
        *(const float4*)&aggL[row][col4];
}

// ---------------- Kernel C: y = agg @ M^T + b2; BN partials ----------------
__global__ __launch_bounds__(256) void kC(const float* __restrict__ aggG,
                                          const float* __restrict__ Mmat,
                                          const float* __restrict__ b2v,
                                          float* __restrict__ y,
                                          float* __restrict__ partial) {
    __shared__ float agg[32][132];
    __shared__ float mc[128][36];
    __shared__ float pw[4][128];
    __shared__ float qw[4][128];
    int t = threadIdx.x;
    int b = blockIdx.x >> 7;
    int n0 = (blockIdx.x & 127) * 32;
    long base = (long)blockIdx.x * (32 * 128);
#pragma unroll
    for (int r = 0; r < 4; ++r) {
        int f = (t + 256*r) * 4;
        int dn = f >> 7, c = f & 127;
        *(float4*)&agg[dn][c] = *(const float4*)(aggG + base + f);
    }
    float acc[4][4] = {};
    int e0 = t & 31, dn0 = (t >> 5) * 4;
    for (int cb = 0; cb < 4; ++cb) {
        __syncthreads();
#pragma unroll
        for (int r = 0; r < 4; ++r) {
            int f = (t + 256*r) * 4;
            int e = f >> 5, cc = f & 31;
            *(float4*)&mc[e][cc] = *(const float4*)(Mmat + e*128 + cb*32 + cc);
        }
        __syncthreads();
#pragma unroll
        for (int q = 0; q < 8; ++q) {
            float4 a4[4], m4[4];
#pragma unroll
            for (int j = 0; j < 4; ++j) a4[j] = *(const float4*)&agg[dn0+j][cb*32 + q*4];
#pragma unroll
            for (int i = 0; i < 4; ++i) m4[i] = *(const float4*)&mc[e0 + 32*i][q*4];
#pragma unroll
            for (int i = 0; i < 4; ++i)
#pragma unroll
                for (int j = 0; j < 4; ++j)
                    acc[i][j] += dot4(a4[j], m4[i]);
        }
        __syncthreads();
    }
    int w = t >> 6;
#pragma unroll
    for (int i = 0; i < 4; ++i) {
        int e = e0 + 32*i;
        float bb = b2v[e];
        float4 yv;
        yv.x = acc[i][0] + bb;
        yv.y = acc[i][1] + bb;
        yv.z = acc[i][2] + bb;
        yv.w = acc[i][3] + bb;
        *(float4*)(y + ((long)(b*CC + e)) * NN + n0 + dn0) = yv;
        float s = yv.x + yv.y + yv.z + yv.w;
        float qq = yv.x*yv.x + yv.y*yv.y + yv.z*yv.z + yv.w*yv.w;
        s  += __shfl_xor(s, 32);
        qq += __shfl_xor(qq, 32);
        if (!(t & 32)) { pw[w][e] = s; qw[w][e] = qq; }
    }
    __syncthreads();
    if (t < 128) {
        partial[(long)blockIdx.x * 256 + t]       = pw[0][t] + pw[1][t] + pw[2][t] + pw[3][t];
        partial[(long)blockIdx.x * 256 + 128 + t] = qw[0][t] + qw[1][t] + qw[2][t] + qw[3][t];
    }
}

// ---------------- Kernel R1: 512 partial rows -> 64 ----------------
__global__ __launch_bounds__(256) void kR1(const float* __restrict__ partial,
                                           float* __restrict__ partial2) {
    int t = threadIdx.x;
    long b0 = (long)blockIdx.x * 8;
    float acc = 0.f;
#pragma unroll
    for (int j = 0; j < 8; ++j)
        acc += partial[(b0 + j) * 256 + t];
    partial2[(long)blockIdx.x * 256 + t] = acc;
}

// ---------------- Kernel Zf: fused stats (64-row reduce, L2-hot) + normalize ----------------
__global__ __launch_bounds__(256) void kZf(float* __restrict__ y,
                                           const float* __restrict__ partial2,
                                           const float* __restrict__ gamma,
                                           const float* __restrict__ beta) {
    __shared__ float buf[256];
    __shared__ float scs[128];
    __shared__ float shs[128];
    int t = threadIdx.x;
    float acc = 0.f;
#pragma unroll 8
    for (int j = 0; j < 64; ++j)
        acc += partial2[j * 256 + t];
    buf[t] = acc;
    __syncthreads();
    if (t < 128) {
        float S = buf[t], Q = buf[t + 128];
        const float invN = 1.0f / (BB * NN);
        float mean = S * invN;
        float var  = Q * invN - mean * mean;
        float sc = rsqrtf(var + 1e-5f) * gamma[t];
        scs[t] = sc;
        shs[t] = beta[t] - mean * sc;
    }
    __syncthreads();
    int idx = blockIdx.x * 256 + t;   // float4 index
#pragma unroll
    for (int r = 0; r < 2; ++r) {
        int i = idx + r * 262144;
        int e = (i >> 10) & 127;
        float sc = scs[e], sh = shs[e];
        float4 v = ((float4*)y)[i];
        v.x = v.x * sc + sh;
        v.y = v.y * sc + sh;
        v.z = v.z * sc + sh;
        v.w = v.w * sc + sh;
        ((float4*)y)[i] = v;
    }
}

extern "C" void kernel_launch(void* const* d_in, const int* in_sizes, int n_in,
                              void* d_out, int out_size, void* d_ws, size_t ws_size,
                              hipStream_t stream) {
    const int*   gi    = (const int*)d_in[0];
    const float* x     = (const float*)d_in[1];
    const float* feat  = (const float*)d_in[2];
    const float* Wt    = (const float*)d_in[3];
    const float* bt    = (const float*)d_in[4];
    const float* Wg    = (const float*)d_in[5];
    const float* bg    = (const float*)d_in[6];
    const float* Ww    = (const float*)d_in[7];
    const float* bw    = (const float*)d_in[8];
    const float* gamma = (const float*)d_in[9];
    const float* beta  = (const float*)d_in[10];

    float* y  = (float*)d_out;
    float* ws = (float*)d_ws;
    float* theta    = ws + THETA_OFF;
    float* aggG     = ws + AGG_OFF;
    float* Mmat     = ws + M_OFF;
    float* b2       = ws + B2_OFF;
    float* coefG    = ws + COEF_OFF;
    float* partial  = ws + PART_OFF;
    float* partial2 = ws + PART2_OFF;

    kWT<<<577, 256, 0, stream>>>(x, Wt, bt, Ww, Wg, bg, bw, theta, Mmat, b2);
    kA<<<1024, 256, 0, stream>>>(gi, theta, coefG);
    kB<<<2048, 256, 0, stream>>>(coefG, feat, aggG);
    kC<<<512, 256, 0, stream>>>(aggG, Mmat, b2, y, partial);
    kR1<<<64, 256, 0, stream>>>(partial, partial2);
    kZf<<<1024, 256, 0, stream>>>(y, partial2, gamma, beta);
}

// Round 9
// 101.326 us; speedup vs baseline: 1.4167x; 1.0114x over previous
//
#include <hip/hip_runtime.h>
#include <hip/hip_bf16.h>

// Problem constants
#define BB 4
#define CC 128
#define NN 4096
#define KK 32
// ws layout (floats)
#define THETA_OFF 0
#define THETA_SZ  (BB*NN*CC)          // 2097152 floats (8 MB)
#define AGG_OFF   (THETA_OFF + THETA_SZ)
#define AGG_SZ    (BB*NN*CC)
#define M_OFF     (AGG_OFF + AGG_SZ)
#define M_SZ      (CC*CC)
#define B2_OFF    (M_OFF + M_SZ)
#define COEF_OFF  (B2_OFF + 128)
#define COEF_SZ   (BB*NN*KK)
#define PART_OFF  (COEF_OFF + COEF_SZ)
#define PART_SZ   (512*256)
#define PART2_OFF (PART_OFF + PART_SZ)
#define PART2_SZ  (64*256)

__device__ __forceinline__ float dot4(float4 a, float4 b) {
    return a.x*b.x + a.y*b.y + a.z*b.z + a.w*b.w;
}

// async global->LDS DMA, 16B per lane. LDS dest is wave-uniform base
// (HW writes base + lane*16); global src is per-lane.
__device__ __forceinline__ void async_copy16(const float* g, float* l) {
    __builtin_amdgcn_global_load_lds(
        (const __attribute__((address_space(1))) void*)g,
        (__attribute__((address_space(3))) void*)l, 16, 0, 0);
}

// ---------------- Kernel WT: theta GEMM (blocks 0..511) + weight combine (512..576) ----
__global__ __launch_bounds__(256) void kWT(const float* __restrict__ x,
                                           const float* __restrict__ Wt,
                                           const float* __restrict__ bt,
                                           const float* __restrict__ Ww,
                                           const float* __restrict__ Wg,
                                           const float* __restrict__ bg,
                                           const float* __restrict__ bw,
                                           float* __restrict__ theta,
                                           float* __restrict__ M,
                                           float* __restrict__ b2) {
    __shared__ float xr[32][132];
    __shared__ float wt[128][36];
    int t = threadIdx.x;
    if (blockIdx.x >= 512) {
        int bid2 = blockIdx.x - 512;
        if (bid2 < 64) {
            int e = bid2 * 2 + (t >> 7);
            int c = t & 127;
            float acc = 0.f;
#pragma unroll 8
            for (int d = 0; d < 128; ++d)
                acc += Ww[e*128 + d] * Wg[d*128 + c];
            M[e*128 + c] = acc;
        } else if (t < 128) {
            float acc = bw[t];
            for (int d = 0; d < 128; ++d)
                acc += Ww[t*128 + d] * bg[d];
            b2[t] = acc;
        }
        return;
    }
    long base = (long)blockIdx.x * (32 * 128);
#pragma unroll
    for (int r = 0; r < 4; ++r) {
        int f = (t + 256*r) * 4;
        int dn = f >> 7, c = f & 127;
        *(float4*)&xr[dn][c] = *(const float4*)(x + base + f);
    }
    float acc[4][4] = {};
    int e0 = t & 31, dn0 = (t >> 5) * 4;
    for (int cb = 0; cb < 4; ++cb) {
        __syncthreads();
#pragma unroll
        for (int r = 0; r < 4; ++r) {
            int f = (t + 256*r) * 4;
            int d = f >> 5, cc = f & 31;
            *(float4*)&wt[d][cc] = *(const float4*)(Wt + d*128 + cb*32 + cc);
        }
        __syncthreads();
#pragma unroll
        for (int q = 0; q < 8; ++q) {
            float4 a4[4], m4[4];
#pragma unroll
            for (int j = 0; j < 4; ++j) a4[j] = *(const float4*)&xr[dn0+j][cb*32 + q*4];
#pragma unroll
            for (int i = 0; i < 4; ++i) m4[i] = *(const float4*)&wt[e0 + 32*i][q*4];
#pragma unroll
            for (int i = 0; i < 4; ++i)
#pragma unroll
                for (int j = 0; j < 4; ++j)
                    acc[i][j] += dot4(a4[j], m4[i]);
        }
    }
    __syncthreads();
#pragma unroll
    for (int i = 0; i < 4; ++i) {
        float b = bt[e0 + 32*i];
#pragma unroll
        for (int j = 0; j < 4; ++j)
            xr[dn0 + j][e0 + 32*i] = acc[i][j] + b;
    }
    __syncthreads();
#pragma unroll
    for (int r = 0; r < 4; ++r) {
        int f = (t + 256*r) * 4;
        int dn = f >> 7, c = f & 127;
        *(float4*)(theta + base + f) = *(const float4*)&xr[dn][c];
    }
}

// ---------------- Kernel A: coef = softmax_k(theta[n] . theta[idx[n,k]]) ----------------
// 8 rows per block, 2048 blocks (8 blocks/CU => 32 waves/CU for gather MLP).
// XCD-bijective swizzle: each XCD works one contiguous half-batch (theta
// working set 2 MB per XCD L2).
__global__ __launch_bounds__(256) void kA(const int* __restrict__ gi,
                                          const float* __restrict__ theta,
                                          float* __restrict__ coefG) {
    __shared__ float tc[8][132];
    __shared__ float logits[8][33];
    int t = threadIdx.x;
    int bid = (blockIdx.x & 7) * 256 + (blockIdx.x >> 3);
    long trow0 = (long)bid * 8;
    int b = bid >> 9;
    int k = t >> 3, l8 = t & 7;
    {
        int f = t * 4;
        int dn = f >> 7, c = f & 127;
        *(float4*)&tc[dn][c] = *(const float4*)(theta + trow0*128 + f);
    }
    int idxs[8];
#pragma unroll
    for (int dn = 0; dn < 8; ++dn)
        idxs[dn] = gi[(trow0 + dn) * KK + k];
    __syncthreads();
    const float* tbat = theta + (long)b * NN * CC;
#pragma unroll 2
    for (int dn = 0; dn < 8; ++dn) {
        const float* row = tbat + (long)idxs[dn] * CC;
        float p = 0.f;
#pragma unroll
        for (int j = 0; j < 4; ++j) {
            int c = j*32 + l8*4;
            float4 g = *(const float4*)(row + c);
            float4 tcv = *(const float4*)&tc[dn][c];
            p += dot4(g, tcv);
        }
        p += __shfl_xor(p, 1);
        p += __shfl_xor(p, 2);
        p += __shfl_xor(p, 4);
        if (l8 == 0) logits[dn][k] = p;
    }
    __syncthreads();
    if (t < 64) {
        int row = t >> 3;
        float l[4];
#pragma unroll
        for (int j = 0; j < 4; ++j) l[j] = logits[row][l8 + 8*j];
        float m = fmaxf(fmaxf(l[0], l[1]), fmaxf(l[2], l[3]));
        m = fmaxf(m, __shfl_xor(m, 1));
        m = fmaxf(m, __shfl_xor(m, 2));
        m = fmaxf(m, __shfl_xor(m, 4));
        float e[4]; float s = 0.f;
#pragma unroll
        for (int j = 0; j < 4; ++j) { e[j] = __expf(l[j] - m); s += e[j]; }
        s += __shfl_xor(s, 1);
        s += __shfl_xor(s, 2);
        s += __shfl_xor(s, 4);
        float inv = 1.0f / s;
#pragma unroll
        for (int j = 0; j < 4; ++j)
            coefG[(trow0 + row) * KK + l8 + 8*j] = e[j] * inv;
    }
}

// ---------------- Kernel B: agg[n][c] = sum_k coef[n][k]*feature[b][c][n][k] ----------------
// Wave-private 2-slot DMA ring: wave w stages channel ch*4+w into its OWN
// 4KB slot and consumes it itself -> NO cross-wave barriers in the loop.
// Per-wave counted vmcnt (4 outstanding while computing, never 0 till last).
// Lane l covers (row = l>>1, k-half = l&1): 4x ds_read_b128 + 4 dot4 + 1 shfl.
__global__ __launch_bounds__(256) void kB(const float* __restrict__ coefG,
                                          const float* __restrict__ feat,
                                          float* __restrict__ aggG) {
    __shared__ float stage[4][2][32][32];   // [wave][slot][n][k] 4x2x4KB
    __shared__ float aggL[32][36];
    int t = threadIdx.x;
    int cc4 = blockIdx.x & 3;
    int tile = blockIdx.x >> 2;          // b*128 + nt
    int b = tile >> 7;
    int n0 = (tile & 127) * 32;
    int w = t >> 6, lane = t & 63;
    int row = lane >> 1, kh = lane & 1;

    // 16 coef floats for (row, k-half), materialized before any DMA issues
    const float* cfp = coefG + ((size_t)tile * 32 + row) * KK + kh * 16;
    float4 cf0 = *(const float4*)(cfp);
    float4 cf1 = *(const float4*)(cfp + 4);
    float4 cf2 = *(const float4*)(cfp + 8);
    float4 cf3 = *(const float4*)(cfp + 12);
    asm volatile("" :: "v"(cf0.x), "v"(cf0.y), "v"(cf0.z), "v"(cf0.w));
    asm volatile("" :: "v"(cf1.x), "v"(cf1.y), "v"(cf1.z), "v"(cf1.w));
    asm volatile("" :: "v"(cf2.x), "v"(cf2.y), "v"(cf2.z), "v"(cf2.w));
    asm volatile("" :: "v"(cf3.x), "v"(cf3.y), "v"(cf3.z), "v"(cf3.w));

    const size_t S = (size_t)NN * KK;
    // per-lane global src: lane L covers bytes [L*16, L*16+16) of each 1KB group
    const float* fbase = feat + ((size_t)b * CC + cc4 * 32) * S + (size_t)n0 * KK + lane * 4;
    float* myStage = &stage[w][0][0][0];

    // prologue: stage chunks 0,1 into this wave's slots 0,1 (channel ch*4+w)
#pragma unroll
    for (int ch = 0; ch < 2; ++ch) {
        const float* fc = fbase + (size_t)(ch * 4 + w) * S;
        float* ld = myStage + ch * 1024;
#pragma unroll
        for (int i = 0; i < 4; ++i)
            async_copy16(fc + i * 256, ld + i * 256);
    }

#pragma unroll
    for (int ch = 0; ch < 8; ++ch) {
        // this wave's oldest 4 DMAs (chunk ch) done; keep next chunk in flight
        if (ch < 7) asm volatile("s_waitcnt vmcnt(4)" ::: "memory");
        else        asm volatile("s_waitcnt vmcnt(0)" ::: "memory");
        const float* sl = myStage + (ch & 1) * 1024 + row * 32 + kh * 16;
        float4 f0 = *(const float4*)(sl);
        float4 f1 = *(const float4*)(sl + 4);
        float4 f2 = *(const float4*)(sl + 8);
        float4 f3 = *(const float4*)(sl + 12);
        float v = dot4(f0, cf0) + dot4(f1, cf1) + dot4(f2, cf2) + dot4(f3, cf3);
        v += __shfl_xor(v, 1);
        if (kh == 0) aggL[row][ch * 4 + w] = v;
        // restage this slot with chunk ch+2 (ds_reads already retired: the
        // dot4s' lgkmcnt wait precedes this issue in program order)
        if (ch + 2 < 8) {
            const float* fc = fbase + (size_t)((ch + 2) * 4 + w) * S;
            float* ld = myStage + (ch & 1) * 1024;
#pragma unroll
            for (int i = 0; i < 4; ++i)
                async_copy16(fc + i * 256, ld + i * 256);
        }
    }
    __syncthreads();
    int orow = t >> 3, col4 = (t & 7) * 4;
    *(float4*)(aggG + ((size_t)b * NN + n0 + orow) * CC + cc4 * 32 + col4) =
        *(const float4*)&aggL[orow][col4];
}

// ---------------- Kernel C: y = agg @ M^T + b2; BN partials ----------------
__global__ __launch_bounds__(256) void kC(const float* __restrict__ aggG,
                                          const float* __restrict__ Mmat,
                                          const float* __restrict__ b2v,
                                          float* __restrict__ y,
                                          float* __restrict__ partial) {
    __shared__ float agg[32][132];
    __shared__ float mc[128][36];
    __shared__ float pw[4][128];
    __shared__ float qw[4][128];
    int t = threadIdx.x;
    int b = blockIdx.x >> 7;
    int n0 = (blockIdx.x & 127) * 32;
    long base = (long)blockIdx.x * (32 * 128);
#pragma unroll
    for (int r = 0; r < 4; ++r) {
        int f = (t + 256*r) * 4;
        int dn = f >> 7, c = f & 127;
        *(float4*)&agg[dn][c] = *(const float4*)(aggG + base + f);
    }
    float acc[4][4] = {};
    int e0 = t & 31, dn0 = (t >> 5) * 4;
    for (int cb = 0; cb < 4; ++cb) {
        __syncthreads();
#pragma unroll
        for (int r = 0; r < 4; ++r) {
            int f = (t + 256*r) * 4;
            int e = f >> 5, cc = f & 31;
            *(float4*)&mc[e][cc] = *(const float4*)(Mmat + e*128 + cb*32 + cc);
        }
        __syncthreads();
#pragma unroll
        for (int q = 0; q < 8; ++q) {
            float4 a4[4], m4[4];
#pragma unroll
            for (int j = 0; j < 4; ++j) a4[j] = *(const float4*)&agg[dn0+j][cb*32 + q*4];
#pragma unroll
            for (int i = 0; i < 4; ++i) m4[i] = *(const float4*)&mc[e0 + 32*i][q*4];
#pragma unroll
            for (int i = 0; i < 4; ++i)
#pragma unroll
                for (int j = 0; j < 4; ++j)
                    acc[i][j] += dot4(a4[j], m4[i]);
        }
        __syncthreads();
    }
    int w = t >> 6;
#pragma unroll
    for (int i = 0; i < 4; ++i) {
        int e = e0 + 32*i;
        float bb = b2v[e];
        float4 yv;
        yv.x = acc[i][0] + bb;
        yv.y = acc[i][1] + bb;
        yv.z = acc[i][2] + bb;
        yv.w = acc[i][3] + bb;
        *(float4*)(y + ((long)(b*CC + e)) * NN + n0 + dn0) = yv;
        float s = yv.x + yv.y + yv.z + yv.w;
        float qq = yv.x*yv.x + yv.y*yv.y + yv.z*yv.z + yv.w*yv.w;
        s  += __shfl_xor(s, 32);
        qq += __shfl_xor(qq, 32);
        if (!(t & 32)) { pw[w][e] = s; qw[w][e] = qq; }
    }
    __syncthreads();
    if (t < 128) {
        partial[(long)blockIdx.x * 256 + t]       = pw[0][t] + pw[1][t] + pw[2][t] + pw[3][t];
        partial[(long)blockIdx.x * 256 + 128 + t] = qw[0][t] + qw[1][t] + qw[2][t] + qw[3][t];
    }
}

// ---------------- Kernel R1: 512 partial rows -> 64 ----------------
__global__ __launch_bounds__(256) void kR1(const float* __restrict__ partial,
                                           float* __restrict__ partial2) {
    int t = threadIdx.x;
    long b0 = (long)blockIdx.x * 8;
    float acc = 0.f;
#pragma unroll
    for (int j = 0; j < 8; ++j)
        acc += partial[(b0 + j) * 256 + t];
    partial2[(long)blockIdx.x * 256 + t] = acc;
}

// ---------------- Kernel Zf: fused stats (64-row reduce, L2-hot) + normalize ----------------
__global__ __launch_bounds__(256) void kZf(float* __restrict__ y,
                                           const float* __restrict__ partial2,
                                           const float* __restrict__ gamma,
                                           const float* __restrict__ beta) {
    __shared__ float buf[256];
    __shared__ float scs[128];
    __shared__ float shs[128];
    int t = threadIdx.x;
    float acc = 0.f;
#pragma unroll 8
    for (int j = 0; j < 64; ++j)
        acc += partial2[j * 256 + t];
    buf[t] = acc;
    __syncthreads();
    if (t < 128) {
        float S = buf[t], Q = buf[t + 128];
        const float invN = 1.0f / (BB * NN);
        float mean = S * invN;
        float var  = Q * invN - mean * mean;
        float sc = rsqrtf(var + 1e-5f) * gamma[t];
        scs[t] = sc;
        shs[t] = beta[t] - mean * sc;
    }
    __syncthreads();
    int idx = blockIdx.x * 256 + t;   // float4 index
#pragma unroll
    for (int r = 0; r < 2; ++r) {
        int i = idx + r * 262144;
        int e = (i >> 10) & 127;
        float sc = scs[e], sh = shs[e];
        float4 v = ((float4*)y)[i];
        v.x = v.x * sc + sh;
        v.y = v.y * sc + sh;
        v.z = v.z * sc + sh;
        v.w = v.w * sc + sh;
        ((float4*)y)[i] = v;
    }
}

extern "C" void kernel_launch(void* const* d_in, const int* in_sizes, int n_in,
                              void* d_out, int out_size, void* d_ws, size_t ws_size,
                              hipStream_t stream) {
    const int*   gi    = (const int*)d_in[0];
    const float* x     = (const float*)d_in[1];
    const float* feat  = (const float*)d_in[2];
    const float* Wt    = (const float*)d_in[3];
    const float* bt    = (const float*)d_in[4];
    const float* Wg    = (const float*)d_in[5];
    const float* bg    = (const float*)d_in[6];
    const float* Ww    = (const float*)d_in[7];
    const float* bw    = (const float*)d_in[8];
    const float* gamma = (const float*)d_in[9];
    const float* beta  = (const float*)d_in[10];

    float* y  = (float*)d_out;
    float* ws = (float*)d_ws;
    float* theta    = ws + THETA_OFF;
    float* aggG     = ws + AGG_OFF;
    float* Mmat     = ws + M_OFF;
    float* b2       = ws + B2_OFF;
    float* coefG    = ws + COEF_OFF;
    float* partial  = ws + PART_OFF;
    float* partial2 = ws + PART2_OFF;

    kWT<<<577, 256, 0, stream>>>(x, Wt, bt, Ww, Wg, bg, bw, theta, Mmat, b2);
    kA<<<2048, 256, 0, stream>>>(gi, theta, coefG);
    kB<<<2048, 256, 0, stream>>>(coefG, feat, aggG);
    kC<<<512, 256, 0, stream>>>(aggG, Mmat, b2, y, partial);
    kR1<<<64, 256, 0, stream>>>(partial, partial2);
    kZf<<<1024, 256, 0, stream>>>(y, partial2, gamma, beta);
}